// Round 1
// baseline (1160.985 us; speedup 1.0000x reference)
//
#include <hip/hip_runtime.h>
#include <hip/hip_bf16.h>

#define HIDDEN 1024
#define NHEAD 16
#define NKV 4
#define HDIM 64
#define KVDIM (NKV * HDIM)   // 256
#define SEQ 2048
#define BATCH 2

// ---------------------------------------------------------------------------
// Tiled fp32 GEMM: C[M,N] = A[M,K] @ W[K,N] + bias[N]
// 64x64 tile, BK=16, 256 threads, 4x4 accum per thread.
// As stored k-major (transposed) with +1 pad; Ws row-major with +1 pad.
// Reads: As broadcast (4 addrs), Ws 2-way (free). M,N,K all multiples of 64/16.
// ---------------------------------------------------------------------------
__global__ __launch_bounds__(256)
void gemm_bias(const float* __restrict__ A, const float* __restrict__ W,
               const float* __restrict__ bias, float* __restrict__ C,
               int M, int N, int K)
{
    __shared__ float As[16][65];   // [k][m]
    __shared__ float Ws[16][65];   // [k][n]
    const int tid  = threadIdx.x;
    const int row0 = blockIdx.y * 64;
    const int col0 = blockIdx.x * 64;
    const int tr   = (tid >> 4) * 4;   // 0..60
    const int tc   = (tid & 15) * 4;   // 0..60
    const int arow = tid >> 2;         // 0..63
    const int ak   = (tid & 3) * 4;    // 0..12
    const int wrow = tid >> 4;         // 0..15
    const int wcol = (tid & 15) * 4;   // 0..60

    float acc[4][4] = {};

    for (int k0 = 0; k0 < K; k0 += 16) {
        float4 av = *(const float4*)(A + (size_t)(row0 + arow) * K + k0 + ak);
        As[ak + 0][arow] = av.x;
        As[ak + 1][arow] = av.y;
        As[ak + 2][arow] = av.z;
        As[ak + 3][arow] = av.w;
        float4 wv = *(const float4*)(W + (size_t)(k0 + wrow) * N + col0 + wcol);
        Ws[wrow][wcol + 0] = wv.x;
        Ws[wrow][wcol + 1] = wv.y;
        Ws[wrow][wcol + 2] = wv.z;
        Ws[wrow][wcol + 3] = wv.w;
        __syncthreads();
#pragma unroll
        for (int k = 0; k < 16; k++) {
            float a[4], b[4];
#pragma unroll
            for (int i = 0; i < 4; i++) { a[i] = As[k][tr + i]; b[i] = Ws[k][tc + i]; }
#pragma unroll
            for (int i = 0; i < 4; i++)
#pragma unroll
                for (int j = 0; j < 4; j++) acc[i][j] += a[i] * b[j];
        }
        __syncthreads();
    }

#pragma unroll
    for (int i = 0; i < 4; i++) {
#pragma unroll
        for (int j = 0; j < 4; j++)
            C[(size_t)(row0 + tr + i) * N + col0 + tc + j] = acc[i][j] + bias[col0 + tc + j];
    }
}

// ---------------------------------------------------------------------------
// Flash-style fused attention, fp32.
// Block = (q-tile of 64 rows, head h, batch b). 256 threads, 4x4 per thread.
// Online softmax with running m,l per q-row (replicated over the 16 lanes of
// a row-group; reduced with __shfl_xor over lane masks 1,2,4,8).
// LDS: Qs[64][64] (unpadded: writes are float4/2-way, reads broadcast)
//      Vs[64][64] (same)
//      KPs[64][65] shared between K-tile (scores) and P (PV) — pad 65 makes
//      the strided Ks[tc+i][d] reads 2-way-free. Total 48.25 KB -> 3 blk/CU.
// ---------------------------------------------------------------------------
__global__ __launch_bounds__(256)
void attn_fused(const float* __restrict__ Q, const float* __restrict__ K,
                const float* __restrict__ V, float* __restrict__ O)
{
    __shared__ float Qs[64][64];
    __shared__ float Vs[64][64];
    __shared__ float KPs[64][65];

    const int tid = threadIdx.x;
    const int qt  = blockIdx.x;
    const int h   = blockIdx.y;
    const int b   = blockIdx.z;
    const int hk  = h >> 2;            // rep = NHEAD/NKV = 4
    const int tr  = (tid >> 4) * 4;
    const int tc  = (tid & 15) * 4;
    const float scale = 0.125f;        // 1/sqrt(64)

    // --- load Q tile (rows qt*64.., dims h*64..) ---
    {
        const float* qbase = Q + ((size_t)(b * SEQ + qt * 64)) * HIDDEN + h * HDIM;
#pragma unroll
        for (int it = 0; it < 4; it++) {
            int idx = tid + it * 256;
            int r = idx >> 4, d = (idx & 15) * 4;
            float4 v = *(const float4*)(qbase + (size_t)r * HIDDEN + d);
            *(float4*)&Qs[r][d] = v;
        }
    }

    float m[4], l[4], acc[4][4];
#pragma unroll
    for (int i = 0; i < 4; i++) {
        m[i] = -1e30f; l[i] = 0.f;
#pragma unroll
        for (int j = 0; j < 4; j++) acc[i][j] = 0.f;
    }

    const float* kbase = K + (size_t)(b * SEQ) * KVDIM + hk * HDIM;
    const float* vbase = V + (size_t)(b * SEQ) * KVDIM + hk * HDIM;

    for (int kt = 0; kt < SEQ / 64; kt++) {
        __syncthreads();   // prior iteration's reads of KPs/Vs complete (also covers Qs load 1st iter)
        // --- load K tile (into KPs) and V tile ---
#pragma unroll
        for (int it = 0; it < 4; it++) {
            int idx = tid + it * 256;
            int r = idx >> 4, d = (idx & 15) * 4;
            float4 kv = *(const float4*)(kbase + (size_t)(kt * 64 + r) * KVDIM + d);
            KPs[r][d + 0] = kv.x; KPs[r][d + 1] = kv.y;
            KPs[r][d + 2] = kv.z; KPs[r][d + 3] = kv.w;
            float4 vv = *(const float4*)(vbase + (size_t)(kt * 64 + r) * KVDIM + d);
            *(float4*)&Vs[r][d] = vv;
        }
        __syncthreads();

        // --- scores S[r][j] = Q[r]·K[j], 4x4 per thread ---
        float s[4][4] = {};
#pragma unroll 8
        for (int d = 0; d < 64; d++) {
            float a[4], bk_[4];
#pragma unroll
            for (int i = 0; i < 4; i++) { a[i] = Qs[tr + i][d]; bk_[i] = KPs[tc + i][d]; }
#pragma unroll
            for (int i = 0; i < 4; i++)
#pragma unroll
                for (int j = 0; j < 4; j++) s[i][j] += a[i] * bk_[j];
        }

        // --- online softmax update ---
        float alpha[4];
#pragma unroll
        for (int i = 0; i < 4; i++) {
#pragma unroll
            for (int j = 0; j < 4; j++) s[i][j] *= scale;
            float mx = fmaxf(fmaxf(s[i][0], s[i][1]), fmaxf(s[i][2], s[i][3]));
            mx = fmaxf(mx, __shfl_xor(mx, 1));
            mx = fmaxf(mx, __shfl_xor(mx, 2));
            mx = fmaxf(mx, __shfl_xor(mx, 4));
            mx = fmaxf(mx, __shfl_xor(mx, 8));
            float mnew = fmaxf(m[i], mx);
            alpha[i] = __expf(m[i] - mnew);
            float rs = 0.f;
#pragma unroll
            for (int j = 0; j < 4; j++) { s[i][j] = __expf(s[i][j] - mnew); rs += s[i][j]; }
            rs += __shfl_xor(rs, 1);
            rs += __shfl_xor(rs, 2);
            rs += __shfl_xor(rs, 4);
            rs += __shfl_xor(rs, 8);
            l[i] = l[i] * alpha[i] + rs;
            m[i] = mnew;
        }

        __syncthreads();   // all score reads of KPs done before overwriting with P
        // --- write P transposed into KPs: KPs[j][r] ---
#pragma unroll
        for (int j = 0; j < 4; j++)
#pragma unroll
            for (int i = 0; i < 4; i++) KPs[tc + j][tr + i] = s[i][j];
        __syncthreads();

        // --- O = O*alpha + P·V ---
#pragma unroll
        for (int i = 0; i < 4; i++)
#pragma unroll
            for (int c = 0; c < 4; c++) acc[i][c] *= alpha[i];
#pragma unroll 8
        for (int j = 0; j < 64; j++) {
            float a[4], bv[4];
#pragma unroll
            for (int i = 0; i < 4; i++) { a[i] = KPs[j][tr + i]; bv[i] = Vs[j][tc + i]; }
#pragma unroll
            for (int i = 0; i < 4; i++)
#pragma unroll
                for (int c = 0; c < 4; c++) acc[i][c] += a[i] * bv[c];
        }
    }

    // --- normalize and write context [b, s, h*64 + d] ---
    float* obase = O + ((size_t)(b * SEQ + qt * 64)) * HIDDEN + h * HDIM;
#pragma unroll
    for (int i = 0; i < 4; i++) {
        float inv = 1.f / l[i];
#pragma unroll
        for (int c = 0; c < 4; c++)
            obase[(size_t)(tr + i) * HIDDEN + tc + c] = acc[i][c] * inv;
    }
}

// ---------------------------------------------------------------------------
extern "C" void kernel_launch(void* const* d_in, const int* in_sizes, int n_in,
                              void* d_out, int out_size, void* d_ws, size_t ws_size,
                              hipStream_t stream)
{
    const float* X  = (const float*)d_in[0];
    const float* Wq = (const float*)d_in[1];
    const float* bq = (const float*)d_in[2];
    const float* Wk = (const float*)d_in[3];
    const float* bk = (const float*)d_in[4];
    const float* Wv = (const float*)d_in[5];
    const float* bv = (const float*)d_in[6];
    const float* Wo = (const float*)d_in[7];
    const float* bo = (const float*)d_in[8];
    float* out = (float*)d_out;

    const int M = BATCH * SEQ;  // 4096
    // workspace layout (fp32): Q [M,1024] | K [M,256] | V [M,256] | Ctx [M,1024]
    char* ws = (char*)d_ws;
    float* Qb  = (float*)(ws);
    float* Kb  = (float*)(ws + (size_t)M * HIDDEN * 4);
    float* Vb  = (float*)(ws + (size_t)M * HIDDEN * 4 + (size_t)M * KVDIM * 4);
    float* Ctx = (float*)(ws + (size_t)M * HIDDEN * 4 + (size_t)2 * M * KVDIM * 4);

    gemm_bias<<<dim3(HIDDEN / 64, M / 64), 256, 0, stream>>>(X, Wq, bq, Qb, M, HIDDEN, HIDDEN);
    gemm_bias<<<dim3(KVDIM  / 64, M / 64), 256, 0, stream>>>(X, Wk, bk, Kb, M, KVDIM, HIDDEN);
    gemm_bias<<<dim3(KVDIM  / 64, M / 64), 256, 0, stream>>>(X, Wv, bv, Vb, M, KVDIM, HIDDEN);

    attn_fused<<<dim3(SEQ / 64, NHEAD, BATCH), 256, 0, stream>>>(Qb, Kb, Vb, Ctx);

    gemm_bias<<<dim3(HIDDEN / 64, M / 64), 256, 0, stream>>>(Ctx, Wo, bo, out, M, HIDDEN, HIDDEN);
}

// Round 2
// 682.585 us; speedup vs baseline: 1.7009x; 1.7009x over previous
//
#include <hip/hip_runtime.h>
#include <hip/hip_bf16.h>

#define HIDDEN 1024
#define NHEAD 16
#define NKV 4
#define HDIM 64
#define KVDIM 256
#define SEQ 2048
#define BATCH 2

typedef __attribute__((ext_vector_type(4))) float f32x4;
typedef __attribute__((ext_vector_type(8))) short s16x8;
typedef __attribute__((ext_vector_type(4))) short s16x4;

static __device__ __forceinline__ ushort f2bf(float f) {
    union { __hip_bfloat16 b; ushort u; } cv;
    cv.b = __float2bfloat16(f);   // RNE
    return cv.u;
}

// ---------------------------------------------------------------------------
// Tiled fp32 GEMM (unchanged from round 1): C[M,N] = A[M,K] @ W[K,N] + bias
// ---------------------------------------------------------------------------
__global__ __launch_bounds__(256)
void gemm_bias(const float* __restrict__ A, const float* __restrict__ W,
               const float* __restrict__ bias, float* __restrict__ C,
               int M, int N, int K)
{
    __shared__ float As[16][65];
    __shared__ float Ws[16][65];
    const int tid  = threadIdx.x;
    const int row0 = blockIdx.y * 64;
    const int col0 = blockIdx.x * 64;
    const int tr   = (tid >> 4) * 4;
    const int tc   = (tid & 15) * 4;
    const int arow = tid >> 2;
    const int ak   = (tid & 3) * 4;
    const int wrow = tid >> 4;
    const int wcol = (tid & 15) * 4;

    float acc[4][4] = {};

    for (int k0 = 0; k0 < K; k0 += 16) {
        float4 av = *(const float4*)(A + (size_t)(row0 + arow) * K + k0 + ak);
        As[ak + 0][arow] = av.x; As[ak + 1][arow] = av.y;
        As[ak + 2][arow] = av.z; As[ak + 3][arow] = av.w;
        float4 wv = *(const float4*)(W + (size_t)(k0 + wrow) * N + col0 + wcol);
        Ws[wrow][wcol + 0] = wv.x; Ws[wrow][wcol + 1] = wv.y;
        Ws[wrow][wcol + 2] = wv.z; Ws[wrow][wcol + 3] = wv.w;
        __syncthreads();
#pragma unroll
        for (int k = 0; k < 16; k++) {
            float a[4], b[4];
#pragma unroll
            for (int i = 0; i < 4; i++) { a[i] = As[k][tr + i]; b[i] = Ws[k][tc + i]; }
#pragma unroll
            for (int i = 0; i < 4; i++)
#pragma unroll
                for (int j = 0; j < 4; j++) acc[i][j] += a[i] * b[j];
        }
        __syncthreads();
    }

#pragma unroll
    for (int i = 0; i < 4; i++)
#pragma unroll
        for (int j = 0; j < 4; j++)
            C[(size_t)(row0 + tr + i) * N + col0 + tc + j] = acc[i][j] + bias[col0 + tc + j];
}

// ---------------------------------------------------------------------------
// fp32 -> bf16 (RNE) with optional scale. n4 = element count / 4.
// ---------------------------------------------------------------------------
__global__ __launch_bounds__(256)
void cvt_bf16(const float* __restrict__ in, ushort* __restrict__ out,
              float scale, int n4)
{
    int i = blockIdx.x * 256 + threadIdx.x;
    if (i >= n4) return;
    float4 v = ((const float4*)in)[i];
    ushort4 o;
    o.x = f2bf(v.x * scale); o.y = f2bf(v.y * scale);
    o.z = f2bf(v.z * scale); o.w = f2bf(v.w * scale);
    ((ushort4*)out)[i] = o;
}

// ---------------------------------------------------------------------------
// V [b][s][hk*64+d] fp32 -> Vt [b][hk][d][s] bf16 (64x64 LDS tile transpose)
// ---------------------------------------------------------------------------
__global__ __launch_bounds__(256)
void vtrans(const float* __restrict__ V, ushort* __restrict__ Vt)
{
    __shared__ float T[64][65];
    const int s0 = blockIdx.x * 64, hk = blockIdx.y, b = blockIdx.z;
    const int tid = threadIdx.x;
#pragma unroll
    for (int it = 0; it < 4; it++) {
        int idx = tid + 256 * it;
        int r = idx >> 4, d4 = (idx & 15) * 4;
        float4 v = *(const float4*)(V + (size_t)(b * SEQ + s0 + r) * KVDIM + hk * HDIM + d4);
        T[r][d4 + 0] = v.x; T[r][d4 + 1] = v.y; T[r][d4 + 2] = v.z; T[r][d4 + 3] = v.w;
    }
    __syncthreads();
#pragma unroll
    for (int it = 0; it < 4; it++) {
        int idx = tid + 256 * it;
        int d = idx >> 4, s4 = (idx & 15) * 4;
        ushort4 o;
        o.x = f2bf(T[s4 + 0][d]); o.y = f2bf(T[s4 + 1][d]);
        o.z = f2bf(T[s4 + 2][d]); o.w = f2bf(T[s4 + 3][d]);
        *(ushort4*)(Vt + ((size_t)((b * NKV + hk) * HDIM + d)) * SEQ + s0 + s4) = o;
    }
}

// ---------------------------------------------------------------------------
// Flash attention, bf16 MFMA 16x16x32.
// Block = (64-row q-tile, head, batch), 4 waves; wave w owns q rows 16w..16w+15.
// Qb pre-scaled by 1/8. Vt is [b][hk][d][s]. O is fp32 ctx [b*s][1024].
// LDS strides: 72 (16B rows -> ds_*_b128, 2-way banks); Ps stride 68
// (conflict-free scalar stores, b64 reads).
// ---------------------------------------------------------------------------
__global__ __launch_bounds__(256)
void attn_mfma(const ushort* __restrict__ Qb, const ushort* __restrict__ Kb,
               const ushort* __restrict__ Vt, float* __restrict__ O)
{
    __shared__ __align__(16) ushort Qs[64][72];
    __shared__ __align__(16) ushort Ks[64][72];
    __shared__ __align__(16) ushort Vs[64][72];   // [d][key]
    __shared__ __align__(16) ushort Ps[64][68];   // [q][key]

    const int tid = threadIdx.x;
    const int w = tid >> 6, lam = tid & 63, c = lam >> 4, m = lam & 15;
    const int q0 = blockIdx.x * 64, h = blockIdx.y, b = blockIdx.z, hk = h >> 2;

    // --- Q tile -> LDS (bf16, pre-scaled) ---
#pragma unroll
    for (int it = 0; it < 2; it++) {
        int idx = tid + 256 * it;
        int r = idx >> 3, col8 = (idx & 7) * 8;
        const ushort* src = Qb + (size_t)(b * SEQ + q0 + r) * HIDDEN + h * HDIM + col8;
        *(s16x8*)&Qs[r][col8] = *(const s16x8*)src;
    }

    float mrow[4], lrow[4];
    f32x4 accv[4];
#pragma unroll
    for (int r = 0; r < 4; r++) {
        mrow[r] = -1e30f; lrow[r] = 0.f;
        accv[r] = (f32x4){0.f, 0.f, 0.f, 0.f};
    }

    const int qrow = 16 * w + m;

    for (int kt = 0; kt < SEQ / 64; kt++) {
        // prefetch K/V tile into registers (global, no LDS dependence)
        s16x8 kreg[2], vreg[2];
#pragma unroll
        for (int it = 0; it < 2; it++) {
            int idx = tid + 256 * it;
            int r = idx >> 3, col8 = (idx & 7) * 8;
            kreg[it] = *(const s16x8*)(Kb + (size_t)(b * SEQ + kt * 64 + r) * KVDIM + hk * HDIM + col8);
            vreg[it] = *(const s16x8*)(Vt + ((size_t)((b * NKV + hk) * HDIM + r)) * SEQ + kt * 64 + col8);
        }
        __syncthreads();   // previous iteration's LDS reads complete
#pragma unroll
        for (int it = 0; it < 2; it++) {
            int idx = tid + 256 * it;
            int r = idx >> 3, col8 = (idx & 7) * 8;
            *(s16x8*)&Ks[r][col8] = kreg[it];
            *(s16x8*)&Vs[r][col8] = vreg[it];
        }
        __syncthreads();

        // --- S = Q K^T (scale pre-folded into Q) ---
        s16x8 aq0 = *(const s16x8*)&Qs[qrow][c * 8];
        s16x8 aq1 = *(const s16x8*)&Qs[qrow][c * 8 + 32];
        f32x4 S[4];
#pragma unroll
        for (int t = 0; t < 4; t++) {
            s16x8 b0 = *(const s16x8*)&Ks[16 * t + m][c * 8];
            s16x8 b1 = *(const s16x8*)&Ks[16 * t + m][c * 8 + 32];
            f32x4 z = {0.f, 0.f, 0.f, 0.f};
            z = __builtin_amdgcn_mfma_f32_16x16x32_bf16(aq0, b0, z, 0, 0, 0);
            S[t] = __builtin_amdgcn_mfma_f32_16x16x32_bf16(aq1, b1, z, 0, 0, 0);
        }

        // --- online softmax; rows handled by this lane: 4c+r, r=0..3 ---
#pragma unroll
        for (int r = 0; r < 4; r++) {
            float mx = fmaxf(fmaxf(S[0][r], S[1][r]), fmaxf(S[2][r], S[3][r]));
            mx = fmaxf(mx, __shfl_xor(mx, 1));
            mx = fmaxf(mx, __shfl_xor(mx, 2));
            mx = fmaxf(mx, __shfl_xor(mx, 4));
            mx = fmaxf(mx, __shfl_xor(mx, 8));
            float mn = fmaxf(mrow[r], mx);
            float al = __expf(mrow[r] - mn);
            float rs = 0.f;
#pragma unroll
            for (int t = 0; t < 4; t++) {
                float p = __expf(S[t][r] - mn);
                S[t][r] = p; rs += p;
            }
            rs += __shfl_xor(rs, 1);
            rs += __shfl_xor(rs, 2);
            rs += __shfl_xor(rs, 4);
            rs += __shfl_xor(rs, 8);
            lrow[r] = lrow[r] * al + rs;
            mrow[r] = mn;
#pragma unroll
            for (int t = 0; t < 4; t++) accv[t][r] *= al;
            // P -> LDS (wave-private rows; in-order DS pipe, no barrier needed)
#pragma unroll
            for (int t = 0; t < 4; t++)
                Ps[16 * w + 4 * c + r][16 * t + m] = f2bf(S[t][r]);
        }

        // --- ctx += P V ---
        s16x4 pa = *(const s16x4*)&Ps[qrow][c * 8];
        s16x4 pb = *(const s16x4*)&Ps[qrow][c * 8 + 4];
        s16x4 pc = *(const s16x4*)&Ps[qrow][c * 8 + 32];
        s16x4 pd = *(const s16x4*)&Ps[qrow][c * 8 + 36];
        s16x8 ap0 = __builtin_shufflevector(pa, pb, 0, 1, 2, 3, 4, 5, 6, 7);
        s16x8 ap1 = __builtin_shufflevector(pc, pd, 0, 1, 2, 3, 4, 5, 6, 7);
#pragma unroll
        for (int t = 0; t < 4; t++) {
            s16x8 v0 = *(const s16x8*)&Vs[16 * t + m][c * 8];
            s16x8 v1 = *(const s16x8*)&Vs[16 * t + m][c * 8 + 32];
            accv[t] = __builtin_amdgcn_mfma_f32_16x16x32_bf16(ap0, v0, accv[t], 0, 0, 0);
            accv[t] = __builtin_amdgcn_mfma_f32_16x16x32_bf16(ap1, v1, accv[t], 0, 0, 0);
        }
    }

    // --- epilogue: O[q][h*64+d] = acc/l ---
    float* obase = O + (size_t)(b * SEQ + q0 + 16 * w) * HIDDEN + h * HDIM;
#pragma unroll
    for (int r = 0; r < 4; r++) {
        float inv = 1.f / lrow[r];
        int row = 4 * c + r;
#pragma unroll
        for (int t = 0; t < 4; t++)
            obase[(size_t)row * HIDDEN + 16 * t + m] = accv[t][r] * inv;
    }
}

// ---------------------------------------------------------------------------
extern "C" void kernel_launch(void* const* d_in, const int* in_sizes, int n_in,
                              void* d_out, int out_size, void* d_ws, size_t ws_size,
                              hipStream_t stream)
{
    const float* X  = (const float*)d_in[0];
    const float* Wq = (const float*)d_in[1];
    const float* bq = (const float*)d_in[2];
    const float* Wk = (const float*)d_in[3];
    const float* bk = (const float*)d_in[4];
    const float* Wv = (const float*)d_in[5];
    const float* bv = (const float*)d_in[6];
    const float* Wo = (const float*)d_in[7];
    const float* bo = (const float*)d_in[8];
    float* out = (float*)d_out;

    const int M = BATCH * SEQ;  // 4096
    // ws layout (36 MB): Qf/Ctx 16MB | Kf 4MB | Vf 4MB | Qbf 8MB | Kbf 2MB | Vt 2MB
    char* ws = (char*)d_ws;
    float*  Qf  = (float*)(ws);
    float*  Ctx = Qf;                       // Qf dead after cvt -> reuse
    float*  Kf  = (float*)(ws + (16u << 20));
    float*  Vf  = (float*)(ws + (20u << 20));
    ushort* Qbf = (ushort*)(ws + (24u << 20));
    ushort* Kbf = (ushort*)(ws + (32u << 20));
    ushort* Vtb = (ushort*)(ws + (34u << 20));

    gemm_bias<<<dim3(HIDDEN / 64, M / 64), 256, 0, stream>>>(X, Wq, bq, Qf, M, HIDDEN, HIDDEN);
    cvt_bf16<<<dim3((M * HIDDEN / 4) / 256), 256, 0, stream>>>(Qf, Qbf, 0.125f, M * HIDDEN / 4);

    gemm_bias<<<dim3(KVDIM / 64, M / 64), 256, 0, stream>>>(X, Wk, bk, Kf, M, KVDIM, HIDDEN);
    cvt_bf16<<<dim3((M * KVDIM / 4) / 256), 256, 0, stream>>>(Kf, Kbf, 1.0f, M * KVDIM / 4);

    gemm_bias<<<dim3(KVDIM / 64, M / 64), 256, 0, stream>>>(X, Wv, bv, Vf, M, KVDIM, HIDDEN);
    vtrans<<<dim3(SEQ / 64, NKV, BATCH), 256, 0, stream>>>(Vf, Vtb);

    attn_mfma<<<dim3(SEQ / 64, NHEAD, BATCH), 256, 0, stream>>>(Qbf, Kbf, Vtb, Ctx);

    gemm_bias<<<dim3(HIDDEN / 64, M / 64), 256, 0, stream>>>(Ctx, Wo, bo, out, M, HIDDEN, HIDDEN);
}

// Round 3
// 310.611 us; speedup vs baseline: 3.7377x; 2.1976x over previous
//
#include <hip/hip_runtime.h>
#include <hip/hip_bf16.h>

#define HIDDEN 1024
#define NHEAD 16
#define NKV 4
#define HDIM 64
#define KVDIM 256
#define SEQ 2048
#define BATCH 2
#define NQKV 1536   // 1024 (Q) + 256 (K) + 256 (V)

typedef __attribute__((ext_vector_type(4))) float f32x4;
typedef __attribute__((ext_vector_type(8))) short s16x8;
typedef __attribute__((ext_vector_type(4))) short s16x4;

static __device__ __forceinline__ ushort f2bf(float f) {
    union { __hip_bfloat16 b; ushort u; } cv; cv.b = __float2bfloat16(f); return cv.u;
}
static __device__ __forceinline__ float bfu2f(ushort u) {
    union { float f; unsigned int i; } cv; cv.i = ((unsigned int)u) << 16; return cv.f;
}
static __device__ __forceinline__ void split2(float v, ushort& h, ushort& l) {
    h = f2bf(v); l = f2bf(v - bfu2f(h));
}
// async global->LDS, 16B per lane. LDS dest = wave-uniform base + lane*16.
static __device__ __forceinline__ void async16(const void* g, void* l) {
    __builtin_amdgcn_global_load_lds((__attribute__((address_space(1))) void*)g,
                                     (__attribute__((address_space(3))) void*)l, 16, 0, 0);
}

// ---------------------------------------------------------------------------
// X fp32 -> hi/lo bf16 planes (elementwise).
// ---------------------------------------------------------------------------
__global__ __launch_bounds__(256)
void split_x(const float* __restrict__ in, ushort* __restrict__ hi,
             ushort* __restrict__ lo)
{
    int i = blockIdx.x * 256 + threadIdx.x;
    float4 v = ((const float4*)in)[i];
    ushort4 h, l;
    split2(v.x, h.x, l.x); split2(v.y, h.y, l.y);
    split2(v.z, h.z, l.z); split2(v.w, h.w, l.w);
    ((ushort4*)hi)[i] = h;
    ((ushort4*)lo)[i] = l;
}

// ---------------------------------------------------------------------------
// W [K][N] fp32 -> transposed split planes T{hi,lo}[roff+n][k] bf16.
// ---------------------------------------------------------------------------
__global__ __launch_bounds__(256)
void wtrans_split(const float* __restrict__ W, ushort* __restrict__ Thi,
                  ushort* __restrict__ Tlo, int roff, int N, int K)
{
    __shared__ float T[64][65];
    const int n0 = blockIdx.x * 64, k0 = blockIdx.y * 64;
    const int tid = threadIdx.x;
#pragma unroll
    for (int it = 0; it < 4; it++) {
        int idx = tid + it * 256;
        int kk = idx >> 4, n4 = (idx & 15) * 4;
        float4 v = *(const float4*)(W + (size_t)(k0 + kk) * N + n0 + n4);
        T[kk][n4 + 0] = v.x; T[kk][n4 + 1] = v.y;
        T[kk][n4 + 2] = v.z; T[kk][n4 + 3] = v.w;
    }
    __syncthreads();
#pragma unroll
    for (int it = 0; it < 4; it++) {
        int idx = tid + it * 256;
        int n = idx >> 4, k4 = (idx & 15) * 4;
        ushort4 h4, l4;
        split2(T[k4 + 0][n], h4.x, l4.x);
        split2(T[k4 + 1][n], h4.y, l4.y);
        split2(T[k4 + 2][n], h4.z, l4.z);
        split2(T[k4 + 3][n], h4.w, l4.w);
        *(ushort4*)(Thi + (size_t)(roff + n0 + n) * K + k0 + k4) = h4;
        *(ushort4*)(Tlo + (size_t)(roff + n0 + n) * K + k0 + k4) = l4;
    }
}

// ---------------------------------------------------------------------------
// Split-bf16 MFMA GEMM: C = (Ahi+Alo)[M,K] @ (Bhi+Blo)^T[N,K] + bias
// (3-term: hi*hi + hi*lo + lo*hi). 128x128 tile, BK=32, 4 waves 2x2,
// each wave 4x4 grid of 16x16x32 MFMAs. global_load_lds width=16 staging.
// MODE 0: bf16 out (QKV buffer, Q cols scaled 0.125, bias from bq/bk/bv)
// MODE 1: fp32 out (+bias b0)
// ---------------------------------------------------------------------------
template <int MODE>
__global__ __launch_bounds__(256)
void gemm_split(const ushort* __restrict__ Ahi, const ushort* __restrict__ Alo,
                const ushort* __restrict__ Bhi, const ushort* __restrict__ Blo,
                const float* __restrict__ b0, const float* __restrict__ b1,
                const float* __restrict__ b2, void* __restrict__ Cout,
                int M, int N, int K)
{
    __shared__ __align__(16) ushort Ah[128 * 32];
    __shared__ __align__(16) ushort Al[128 * 32];
    __shared__ __align__(16) ushort Bh[128 * 32];
    __shared__ __align__(16) ushort Bl[128 * 32];

    const int tid = threadIdx.x;
    const int lane = tid & 63, wv = tid >> 6;
    const int wr = wv >> 1, wc = wv & 1;
    const int m = lane & 15, c = lane >> 4;
    const int row0 = blockIdx.y * 128, col0 = blockIdx.x * 128;

    // staging addressing: idx = it*256+tid covers 16B: row = idx>>2, col8 = (idx&3)*8
    const ushort* gA0[2]; const ushort* gA1[2];
    const ushort* gB0[2]; const ushort* gB1[2];
    int ldsOff[2];
#pragma unroll
    for (int it = 0; it < 2; it++) {
        int idx = it * 256 + tid;
        int r = idx >> 2, cb = (idx & 3) * 8;
        gA0[it] = Ahi + (size_t)(row0 + r) * K + cb;
        gA1[it] = Alo + (size_t)(row0 + r) * K + cb;
        gB0[it] = Bhi + (size_t)(col0 + r) * K + cb;
        gB1[it] = Blo + (size_t)(col0 + r) * K + cb;
        ldsOff[it] = (it * 256 + wv * 64) * 8;   // wave-uniform element offset
    }

    f32x4 acc[4][4];
#pragma unroll
    for (int t = 0; t < 4; t++)
#pragma unroll
        for (int u = 0; u < 4; u++) acc[t][u] = (f32x4){0.f, 0.f, 0.f, 0.f};

    for (int k0 = 0; k0 < K; k0 += 32) {
        __syncthreads();   // all waves done reading previous chunk
#pragma unroll
        for (int it = 0; it < 2; it++) {
            async16(gA0[it] + k0, Ah + ldsOff[it]);
            async16(gA1[it] + k0, Al + ldsOff[it]);
            async16(gB0[it] + k0, Bh + ldsOff[it]);
            async16(gB1[it] + k0, Bl + ldsOff[it]);
        }
        __syncthreads();   // staging complete (barrier drains vmcnt)

        s16x8 ah[4], al[4], bh[4], bl[4];
#pragma unroll
        for (int t = 0; t < 4; t++) {
            int ra = (64 * wr + 16 * t + m) * 32 + c * 8;
            int rb = (64 * wc + 16 * t + m) * 32 + c * 8;
            ah[t] = *(const s16x8*)&Ah[ra];
            al[t] = *(const s16x8*)&Al[ra];
            bh[t] = *(const s16x8*)&Bh[rb];
            bl[t] = *(const s16x8*)&Bl[rb];
        }
#pragma unroll
        for (int t = 0; t < 4; t++)
#pragma unroll
            for (int u = 0; u < 4; u++) {
                acc[t][u] = __builtin_amdgcn_mfma_f32_16x16x32_bf16(ah[t], bh[u], acc[t][u], 0, 0, 0);
                acc[t][u] = __builtin_amdgcn_mfma_f32_16x16x32_bf16(ah[t], bl[u], acc[t][u], 0, 0, 0);
                acc[t][u] = __builtin_amdgcn_mfma_f32_16x16x32_bf16(al[t], bh[u], acc[t][u], 0, 0, 0);
            }
    }

    const int orow = row0 + 64 * wr + 4 * c;   // + 16t + r
    const int ocol = col0 + 64 * wc + m;       // + 16u
    if (MODE == 0) {
        ushort* Cb = (ushort*)Cout;
#pragma unroll
        for (int u = 0; u < 4; u++) {
            int n = ocol + 16 * u;
            float bias, scl;
            if (n < 1024)      { bias = b0[n];        scl = 0.125f; }
            else if (n < 1280) { bias = b1[n - 1024]; scl = 1.0f; }
            else               { bias = b2[n - 1280]; scl = 1.0f; }
#pragma unroll
            for (int t = 0; t < 4; t++)
#pragma unroll
                for (int r = 0; r < 4; r++)
                    Cb[(size_t)(orow + 16 * t + r) * N + n] = f2bf((acc[t][u][r] + bias) * scl);
        }
    } else {
        float* Cf = (float*)Cout;
#pragma unroll
        for (int u = 0; u < 4; u++) {
            int n = ocol + 16 * u;
            float bias = b0[n];
#pragma unroll
            for (int t = 0; t < 4; t++)
#pragma unroll
                for (int r = 0; r < 4; r++)
                    Cf[(size_t)(orow + 16 * t + r) * N + n] = acc[t][u][r] + bias;
        }
    }
}

// ---------------------------------------------------------------------------
// V columns of QKV buffer (bf16, stride NQKV) -> Vt [b][hk][d][s] bf16.
// ---------------------------------------------------------------------------
__global__ __launch_bounds__(256)
void vtrans_bf(const ushort* __restrict__ QKV, ushort* __restrict__ Vt)
{
    __shared__ ushort T[64][65];
    const int s0 = blockIdx.x * 64, hk = blockIdx.y, b = blockIdx.z;
    const int tid = threadIdx.x;
#pragma unroll
    for (int it = 0; it < 4; it++) {
        int idx = tid + it * 256;
        int r = idx >> 4, d4 = (idx & 15) * 4;
        ushort4 v = *(const ushort4*)(QKV + (size_t)(b * SEQ + s0 + r) * NQKV + 1280 + hk * HDIM + d4);
        T[r][d4 + 0] = v.x; T[r][d4 + 1] = v.y;
        T[r][d4 + 2] = v.z; T[r][d4 + 3] = v.w;
    }
    __syncthreads();
#pragma unroll
    for (int it = 0; it < 4; it++) {
        int idx = tid + it * 256;
        int d = idx >> 4, s4 = (idx & 15) * 4;
        ushort4 o;
        o.x = T[s4 + 0][d]; o.y = T[s4 + 1][d];
        o.z = T[s4 + 2][d]; o.w = T[s4 + 3][d];
        *(ushort4*)(Vt + ((size_t)((b * NKV + hk) * HDIM + d)) * SEQ + s0 + s4) = o;
    }
}

// ---------------------------------------------------------------------------
// Flash attention, bf16 MFMA 16x16x32 (round-2 structure).
// Q from QKV cols [h*64, +64) (pre-scaled 0.125 in GEMM epilogue),
// K from cols [1024 + hk*64, +64), V from Vt [b][hk][d][s].
// Output: Ctx hi/lo split bf16 planes [4096][1024].
// ---------------------------------------------------------------------------
__global__ __launch_bounds__(256)
void attn_mfma(const ushort* __restrict__ QKV, const ushort* __restrict__ Vt,
               ushort* __restrict__ Chi, ushort* __restrict__ Clo)
{
    __shared__ __align__(16) ushort Qs[64][72];
    __shared__ __align__(16) ushort Ks[64][72];
    __shared__ __align__(16) ushort Vs[64][72];   // [d][key]
    __shared__ __align__(16) ushort Ps[64][68];   // [q][key]

    const int tid = threadIdx.x;
    const int w = tid >> 6, lam = tid & 63, c = lam >> 4, m = lam & 15;
    const int q0 = blockIdx.x * 64, h = blockIdx.y, b = blockIdx.z, hk = h >> 2;

#pragma unroll
    for (int it = 0; it < 2; it++) {
        int idx = tid + 256 * it;
        int r = idx >> 3, col8 = (idx & 7) * 8;
        const ushort* src = QKV + (size_t)(b * SEQ + q0 + r) * NQKV + h * HDIM + col8;
        *(s16x8*)&Qs[r][col8] = *(const s16x8*)src;
    }

    float mrow[4], lrow[4];
    f32x4 accv[4];
#pragma unroll
    for (int r = 0; r < 4; r++) {
        mrow[r] = -1e30f; lrow[r] = 0.f;
        accv[r] = (f32x4){0.f, 0.f, 0.f, 0.f};
    }

    const int qrow = 16 * w + m;
    const ushort* kbase = QKV + (size_t)(b * SEQ) * NQKV + 1024 + hk * HDIM;
    const ushort* vbase = Vt + ((size_t)((b * NKV + hk) * HDIM)) * SEQ;

    for (int kt = 0; kt < SEQ / 64; kt++) {
        s16x8 kreg[2], vreg[2];
#pragma unroll
        for (int it = 0; it < 2; it++) {
            int idx = tid + 256 * it;
            int r = idx >> 3, col8 = (idx & 7) * 8;
            kreg[it] = *(const s16x8*)(kbase + (size_t)(kt * 64 + r) * NQKV + col8);
            vreg[it] = *(const s16x8*)(vbase + (size_t)r * SEQ + kt * 64 + col8);
        }
        __syncthreads();
#pragma unroll
        for (int it = 0; it < 2; it++) {
            int idx = tid + 256 * it;
            int r = idx >> 3, col8 = (idx & 7) * 8;
            *(s16x8*)&Ks[r][col8] = kreg[it];
            *(s16x8*)&Vs[r][col8] = vreg[it];
        }
        __syncthreads();

        s16x8 aq0 = *(const s16x8*)&Qs[qrow][c * 8];
        s16x8 aq1 = *(const s16x8*)&Qs[qrow][c * 8 + 32];
        f32x4 S[4];
#pragma unroll
        for (int t = 0; t < 4; t++) {
            s16x8 b0 = *(const s16x8*)&Ks[16 * t + m][c * 8];
            s16x8 b1 = *(const s16x8*)&Ks[16 * t + m][c * 8 + 32];
            f32x4 z = {0.f, 0.f, 0.f, 0.f};
            z = __builtin_amdgcn_mfma_f32_16x16x32_bf16(aq0, b0, z, 0, 0, 0);
            S[t] = __builtin_amdgcn_mfma_f32_16x16x32_bf16(aq1, b1, z, 0, 0, 0);
        }

#pragma unroll
        for (int r = 0; r < 4; r++) {
            float mx = fmaxf(fmaxf(S[0][r], S[1][r]), fmaxf(S[2][r], S[3][r]));
            mx = fmaxf(mx, __shfl_xor(mx, 1));
            mx = fmaxf(mx, __shfl_xor(mx, 2));
            mx = fmaxf(mx, __shfl_xor(mx, 4));
            mx = fmaxf(mx, __shfl_xor(mx, 8));
            float mn = fmaxf(mrow[r], mx);
            float al = __expf(mrow[r] - mn);
            float rs = 0.f;
#pragma unroll
            for (int t = 0; t < 4; t++) {
                float p = __expf(S[t][r] - mn);
                S[t][r] = p; rs += p;
            }
            rs += __shfl_xor(rs, 1);
            rs += __shfl_xor(rs, 2);
            rs += __shfl_xor(rs, 4);
            rs += __shfl_xor(rs, 8);
            lrow[r] = lrow[r] * al + rs;
            mrow[r] = mn;
#pragma unroll
            for (int t = 0; t < 4; t++) accv[t][r] *= al;
#pragma unroll
            for (int t = 0; t < 4; t++)
                Ps[16 * w + 4 * c + r][16 * t + m] = f2bf(S[t][r]);
        }

        s16x4 pa = *(const s16x4*)&Ps[qrow][c * 8];
        s16x4 pb = *(const s16x4*)&Ps[qrow][c * 8 + 4];
        s16x4 pc = *(const s16x4*)&Ps[qrow][c * 8 + 32];
        s16x4 pd = *(const s16x4*)&Ps[qrow][c * 8 + 36];
        s16x8 ap0 = __builtin_shufflevector(pa, pb, 0, 1, 2, 3, 4, 5, 6, 7);
        s16x8 ap1 = __builtin_shufflevector(pc, pd, 0, 1, 2, 3, 4, 5, 6, 7);
#pragma unroll
        for (int t = 0; t < 4; t++) {
            s16x8 v0 = *(const s16x8*)&Vs[16 * t + m][c * 8];
            s16x8 v1 = *(const s16x8*)&Vs[16 * t + m][c * 8 + 32];
            accv[t] = __builtin_amdgcn_mfma_f32_16x16x32_bf16(ap0, v0, accv[t], 0, 0, 0);
            accv[t] = __builtin_amdgcn_mfma_f32_16x16x32_bf16(ap1, v1, accv[t], 0, 0, 0);
        }
    }

    size_t rbase = (size_t)(b * SEQ + q0 + 16 * w) * HIDDEN + h * HDIM;
#pragma unroll
    for (int r = 0; r < 4; r++) {
        float inv = 1.f / lrow[r];
        int row = 4 * c + r;
#pragma unroll
        for (int t = 0; t < 4; t++) {
            float v = accv[t][r] * inv;
            ushort hh, ll; split2(v, hh, ll);
            Chi[rbase + (size_t)row * HIDDEN + 16 * t + m] = hh;
            Clo[rbase + (size_t)row * HIDDEN + 16 * t + m] = ll;
        }
    }
}

// ---------------------------------------------------------------------------
extern "C" void kernel_launch(void* const* d_in, const int* in_sizes, int n_in,
                              void* d_out, int out_size, void* d_ws, size_t ws_size,
                              hipStream_t stream)
{
    const float* X  = (const float*)d_in[0];
    const float* Wq = (const float*)d_in[1];
    const float* bq = (const float*)d_in[2];
    const float* Wk = (const float*)d_in[3];
    const float* bk = (const float*)d_in[4];
    const float* Wv = (const float*)d_in[5];
    const float* bv = (const float*)d_in[6];
    const float* Wo = (const float*)d_in[7];
    const float* bo = (const float*)d_in[8];
    float* out = (float*)d_out;

    const int M = BATCH * SEQ;  // 4096
    // ws layout (40 MB total):
    //  0: Xhi 8MB (CtxHi aliases after QKV gemm)   8: Xlo 8MB (CtxLo alias)
    // 16: QKVb bf16 [4096][1536] 12MB
    // 28: WqkvHi 3MB   31: WqkvLo 3MB
    // 34: WotHi 2MB    36: WotLo 2MB    38: Vt 2MB
    char* ws = (char*)d_ws;
    ushort* Xhi    = (ushort*)(ws);
    ushort* Xlo    = (ushort*)(ws + (8u  << 20));
    ushort* CtxHi  = Xhi;
    ushort* CtxLo  = Xlo;
    ushort* QKVb   = (ushort*)(ws + (16u << 20));
    ushort* WqkvHi = (ushort*)(ws + (28u << 20));
    ushort* WqkvLo = (ushort*)(ws + (31u << 20));
    ushort* WotHi  = (ushort*)(ws + (34u << 20));
    ushort* WotLo  = (ushort*)(ws + (36u << 20));
    ushort* Vtb    = (ushort*)(ws + (38u << 20));

    split_x<<<dim3(M * HIDDEN / 4 / 256), 256, 0, stream>>>(X, Xhi, Xlo);
    wtrans_split<<<dim3(16, 16), 256, 0, stream>>>(Wq, WqkvHi, WqkvLo, 0,    1024, HIDDEN);
    wtrans_split<<<dim3(4, 16),  256, 0, stream>>>(Wk, WqkvHi, WqkvLo, 1024, 256,  HIDDEN);
    wtrans_split<<<dim3(4, 16),  256, 0, stream>>>(Wv, WqkvHi, WqkvLo, 1280, 256,  HIDDEN);
    wtrans_split<<<dim3(16, 16), 256, 0, stream>>>(Wo, WotHi,  WotLo,  0,    1024, HIDDEN);

    gemm_split<0><<<dim3(NQKV / 128, M / 128), 256, 0, stream>>>(
        Xhi, Xlo, WqkvHi, WqkvLo, bq, bk, bv, (void*)QKVb, M, NQKV, HIDDEN);

    vtrans_bf<<<dim3(SEQ / 64, NKV, BATCH), 256, 0, stream>>>(QKVb, Vtb);

    attn_mfma<<<dim3(SEQ / 64, NHEAD, BATCH), 256, 0, stream>>>(QKVb, Vtb, CtxHi, CtxLo);

    gemm_split<1><<<dim3(HIDDEN / 128, M / 128), 256, 0, stream>>>(
        CtxHi, CtxLo, WotHi, WotLo, bo, nullptr, nullptr, (void*)out, M, HIDDEN, HIDDEN);
}